// Round 2
// baseline (2052.866 us; speedup 1.0000x reference)
//
#include <hip/hip_runtime.h>
#include <hip/hip_bf16.h>
#include <math.h>

#define NPTS 2048
#define NCLOUD 32
#define NTOT (NPTS*NCLOUD)
#define CIN 64
#define COUT 128
#define KNN 16
#define KCAND 20
#define TC 128   // K1 column tile

// ---------------- K1: per-row fp32 ranking, keep top-KCAND candidates ----------------
__global__ __launch_bounds__(256,1) void k1_knn(const float* __restrict__ x, int* __restrict__ cand)
{
    __shared__ float xt[TC*68];   // [col][68] padded (272B rows, 16B aligned)
    __shared__ float sqq[TC];
    const int b     = blockIdx.x >> 3;          // 8 blocks per cloud
    const int rbase = (blockIdx.x & 7) * 256;
    const int t     = threadIdx.x;
    const int p     = rbase + t;                // my row within cloud
    const float* xc = x + (size_t)b * NPTS * CIN;

    float xp[CIN];
    #pragma unroll
    for (int i = 0; i < CIN/4; ++i) {
        float4 v = *reinterpret_cast<const float4*>(xc + (size_t)p*CIN + 4*i);
        xp[4*i+0]=v.x; xp[4*i+1]=v.y; xp[4*i+2]=v.z; xp[4*i+3]=v.w;
    }

    // sorted descending: ld[0] = worst kept, ld[KCAND-1] = best
    float ld[KCAND]; int li[KCAND];
    #pragma unroll
    for (int j = 0; j < KCAND; ++j) { ld[j] = INFINITY; li[j] = 0; }

    for (int tile = 0; tile < NPTS/TC; ++tile) {
        __syncthreads();
        if (t < TC) {
            const float* src = xc + (size_t)(tile*TC + t) * CIN;
            float s = 0.f;
            #pragma unroll
            for (int i = 0; i < CIN/4; ++i) {
                float4 v = *reinterpret_cast<const float4*>(src + 4*i);
                *reinterpret_cast<float4*>(&xt[t*68 + 4*i]) = v;
                s += v.x*v.x + v.y*v.y + v.z*v.z + v.w*v.w;
            }
            sqq[t] = s;
        }
        __syncthreads();
        const int gbase = tile * TC;
        for (int q = 0; q < TC; ++q) {
            float a0=0.f,a1=0.f,a2=0.f,a3=0.f;
            #pragma unroll
            for (int i = 0; i < CIN/4; ++i) {
                float4 v = *reinterpret_cast<const float4*>(&xt[q*68 + 4*i]); // wave-uniform: LDS broadcast
                a0 = fmaf(v.x, xp[4*i+0], a0);
                a1 = fmaf(v.y, xp[4*i+1], a1);
                a2 = fmaf(v.z, xp[4*i+2], a2);
                a3 = fmaf(v.w, xp[4*i+3], a3);
            }
            float s = sqq[q] - 2.f*((a0+a1)+(a2+a3));   // = d^2 - |p|^2 (rank-equivalent per row)
            const int gq = gbase + q;
            if (s < ld[0] && gq != p) {
                ld[0] = s; li[0] = gq;
                #pragma unroll
                for (int j = 0; j < KCAND-1; ++j) {     // one bubble pass, static indices
                    if (ld[j] < ld[j+1]) {
                        float td = ld[j]; ld[j] = ld[j+1]; ld[j+1] = td;
                        int   ti = li[j]; li[j] = li[j+1]; li[j+1] = ti;
                    }
                }
            }
        }
    }
    int* dst = cand + (size_t)(b*NPTS + p) * KCAND;
    #pragma unroll
    for (int j = 0; j < KCAND; ++j) dst[j] = li[j];
}

// np.sum pairwise-8 replication for 64 squares: r[j] += v[8i+j]^2, then
// ((r0+r1)+(r2+r3)) + ((r4+r5)+(r6+r7)) — all fp32, no FMA contraction.
__device__ __forceinline__ float np_sq64(const float* __restrict__ v)
{
    float r[8];
    #pragma unroll
    for (int j = 0; j < 8; ++j) r[j] = __fmul_rn(v[j], v[j]);
    #pragma unroll
    for (int i = 1; i < 8; ++i)
        #pragma unroll
        for (int j = 0; j < 8; ++j) r[j] = __fadd_rn(r[j], __fmul_rn(v[8*i+j], v[8*i+j]));
    return __fadd_rn(__fadd_rn(__fadd_rn(r[0],r[1]), __fadd_rn(r[2],r[3])),
                     __fadd_rn(__fadd_rn(r[4],r[5]), __fadd_rn(r[6],r[7])));
}

// ---------------- K2: fp32-faithful rerank of the KCAND candidates -> top-16 set ----------------
// Ranks by d = fl32(sqp+sqq) - fl32(2*dot) with index tie-break, matching
// fp32 top_k(-d) semantics of the reference (ties -> lower index).
__global__ void k2_refine(const float* __restrict__ x, const int* __restrict__ cand, int* __restrict__ nbr)
{
    const int gtid = blockIdx.x * blockDim.x + threadIdx.x;
    const int w    = gtid >> 6;                 // point id (one wave per point)
    const int lane = threadIdx.x & 63;
    const int b    = w >> 11;
    const int p    = w & (NPTS-1);
    const float* xc = x + (size_t)b * NPTS * CIN;
    const float* xp = xc + (size_t)p * CIN;

    float d = INFINITY; int q = 0x7fffffff;
    if (lane < KCAND) {
        q = cand[(size_t)w * KCAND + lane];
        const float* xq = xc + (size_t)q * CIN;
        const float sqp = np_sq64(xp);
        const float sqq = np_sq64(xq);
        float dot = 0.f;                         // sequential fp32, no FMA
        #pragma unroll
        for (int c = 0; c < CIN; ++c) dot = __fadd_rn(dot, __fmul_rn(xp[c], xq[c]));
        d = __fsub_rn(__fadd_rn(sqp, sqq), __fmul_rn(2.f, dot));
    }
    int rank = 0;
    #pragma unroll
    for (int j = 0; j < KCAND; ++j) {
        float dj = __shfl(d, j);
        int   qj = __shfl(q, j);
        if (dj < d || (dj == d && qj < q)) ++rank;   // lower index wins ties
    }
    if (lane < KCAND && rank < KNN)
        nbr[(size_t)w * KNN + rank] = b * NPTS + q;   // global neighbor id
}

// ---------------- K3: scatter-max pooled[n] = max over centers c with n in knn(c) of x[c] ----------------
__global__ void k3_scatter(const float* __restrict__ x, const int* __restrict__ nbr, float* __restrict__ pooled)
{
    const int gtid = blockIdx.x * blockDim.x + threadIdx.x;
    const int c    = gtid >> 6;                 // center point, one wave each
    const int lane = threadIdx.x & 63;          // channel
    const float v  = x[(size_t)c * CIN + lane];
    const int   vi = __float_as_int(v);
    const unsigned vu = __float_as_uint(v);
    #pragma unroll
    for (int k = 0; k < KNN; ++k) {
        const int n = nbr[(size_t)c * KNN + k];
        float* addr = &pooled[(size_t)n * CIN + lane];
        if (v >= 0.f) atomicMax((int*)addr, vi);        // pos floats: int order == float order
        else          atomicMin((unsigned*)addr, vu);   // neg floats: uint order reversed
    }
}

// ---------------- K4: y = pooled @ W^T + b (64x128 tile per block) ----------------
__global__ __launch_bounds__(256,2) void k4_linear(const float* __restrict__ pooled, const float* __restrict__ W,
                                                   const float* __restrict__ bias, float* __restrict__ y)
{
    __shared__ float wl[COUT*68];   // [c][k] padded
    __shared__ float pl[64*68];     // [r][k] padded
    const int t  = threadIdx.x;
    const int r0 = blockIdx.x * 64;
    for (int i = 0; i < (COUT*CIN)/256; ++i) {          // 32 iters
        int linear = t + 256*i;
        int c = linear >> 6, k = linear & 63;
        wl[c*68 + k] = W[linear];
    }
    for (int i = 0; i < (64*CIN)/256; ++i) {            // 16 iters
        int linear = t + 256*i;
        int r = linear >> 6, k = linear & 63;
        float v = pooled[(size_t)(r0 + r)*CIN + k];
        if (v != v) v = 0.f;                            // NaN marker = empty row -> 0
        pl[r*68 + k] = v;
    }
    __syncthreads();
    const int tx = t & 15;          // cols c = tx + 16*j
    const int ty = t >> 4;          // rows r = ty*4 + i
    float acc[4][8];
    #pragma unroll
    for (int j = 0; j < 8; ++j) {
        float bj = bias[tx + 16*j];
        #pragma unroll
        for (int i = 0; i < 4; ++i) acc[i][j] = bj;
    }
    for (int k = 0; k < CIN; k += 4) {
        float4 a[4], bb[8];
        #pragma unroll
        for (int i = 0; i < 4; ++i) a[i]  = *reinterpret_cast<const float4*>(&pl[(ty*4+i)*68 + k]);
        #pragma unroll
        for (int j = 0; j < 8; ++j) bb[j] = *reinterpret_cast<const float4*>(&wl[(tx+16*j)*68 + k]);
        #pragma unroll
        for (int i = 0; i < 4; ++i)
            #pragma unroll
            for (int j = 0; j < 8; ++j) {
                acc[i][j] = fmaf(a[i].x, bb[j].x, acc[i][j]);
                acc[i][j] = fmaf(a[i].y, bb[j].y, acc[i][j]);
                acc[i][j] = fmaf(a[i].z, bb[j].z, acc[i][j]);
                acc[i][j] = fmaf(a[i].w, bb[j].w, acc[i][j]);
            }
    }
    #pragma unroll
    for (int i = 0; i < 4; ++i) {
        float* dst = y + (size_t)(r0 + ty*4 + i) * COUT;
        #pragma unroll
        for (int j = 0; j < 8; ++j) dst[tx + 16*j] = acc[i][j];
    }
}

// ---------------- K5: per-channel sum / sumsq over all rows (fp64 accumulation) ----------------
__global__ void k5_stats(const float* __restrict__ y, double* __restrict__ sums)
{
    __shared__ double red[512];
    const int t    = threadIdx.x;
    const int ch   = t & 127;
    const int half = t >> 7;
    const size_t base = (size_t)blockIdx.x * 256;
    double s = 0.0, ss = 0.0;
    for (int r = 0; r < 128; ++r) {
        double v = (double)y[(base + (size_t)half*128 + r) * COUT + ch];
        s += v; ss += v*v;
    }
    red[t] = s; red[256 + t] = ss;
    __syncthreads();
    if (half == 0) {
        atomicAdd(&sums[ch],        s  + red[128 + ch]);
        atomicAdd(&sums[COUT + ch], ss + red[256 + 128 + ch]);
    }
}

// ---------------- K6: BN scale/shift ----------------
__global__ void k6_bnparam(const double* __restrict__ sums, const float* __restrict__ gamma,
                           const float* __restrict__ beta, float* __restrict__ scsh)
{
    const int t = threadIdx.x;
    const double mean = sums[t] * (1.0/NTOT);
    const double var  = sums[COUT + t] * (1.0/NTOT) - mean*mean;
    const float inv   = (float)rsqrt(var + 1e-5);
    const float sc    = inv * gamma[t];
    scsh[t]        = sc;
    scsh[COUT + t] = beta[t] - (float)mean * sc;
}

// ---------------- K7: out = relu(y*scale + shift) ----------------
__global__ void k7_bnrelu(const float* __restrict__ y, const float* __restrict__ scsh, float* __restrict__ out)
{
    const int g    = blockIdx.x * blockDim.x + threadIdx.x;
    const int base = g * 4;
    float4 v = *reinterpret_cast<const float4*>(y + base);
    const int ch = base & (COUT-1);
    float4 o;
    o.x = fmaxf(0.f, fmaf(v.x, scsh[ch+0], scsh[COUT+ch+0]));
    o.y = fmaxf(0.f, fmaf(v.y, scsh[ch+1], scsh[COUT+ch+1]));
    o.z = fmaxf(0.f, fmaf(v.z, scsh[ch+2], scsh[COUT+ch+2]));
    o.w = fmaxf(0.f, fmaf(v.w, scsh[ch+3], scsh[COUT+ch+3]));
    *reinterpret_cast<float4*>(out + base) = o;
}

extern "C" void kernel_launch(void* const* d_in, const int* in_sizes, int n_in,
                              void* d_out, int out_size, void* d_ws, size_t ws_size,
                              hipStream_t stream)
{
    const float* x     = (const float*)d_in[0];
    // d_in[1] = batch (int64) — layout is fixed (B clouds of P), unused
    const float* W     = (const float*)d_in[2];
    const float* bias  = (const float*)d_in[3];
    const float* gamma = (const float*)d_in[4];
    const float* beta  = (const float*)d_in[5];
    float* out = (float*)d_out;

    char* ws = (char*)d_ws;
    int*    cand   = (int*)ws;                                        // NTOT*20 ints
    int*    nbr    = (int*)(ws + (size_t)NTOT*KCAND*4);               // NTOT*16 ints
    float*  pooled = (float*)(ws + (size_t)NTOT*(KCAND+KNN)*4);       // NTOT*64 f32
    float*  y      = (float*)(ws + (size_t)NTOT*(KCAND+KNN+CIN)*4);   // NTOT*128 f32
    double* sums   = (double*)(ws + (size_t)NTOT*(KCAND+KNN+CIN+COUT)*4); // 2*COUT f64 (8B aligned)
    float*  scsh   = (float*)((char*)sums + 2*COUT*sizeof(double));

    hipMemsetAsync(pooled, 0xFF, (size_t)NTOT*CIN*4, stream);  // all-ones = NaN marker ("-inf" for the atomic trick)
    hipMemsetAsync(sums, 0, 2*COUT*sizeof(double), stream);

    k1_knn   <<<NCLOUD*8,        256, 0, stream>>>(x, cand);
    k2_refine<<<NTOT/4,          256, 0, stream>>>(x, cand, nbr);
    k3_scatter<<<NTOT/4,         256, 0, stream>>>(x, nbr, pooled);
    k4_linear<<<NTOT/64,         256, 0, stream>>>(pooled, W, bias, y);
    k5_stats <<<NTOT/256,        256, 0, stream>>>(y, sums);
    k6_bnparam<<<1,             COUT, 0, stream>>>(sums, gamma, beta, scsh);
    k7_bnrelu<<<(NTOT*COUT/4)/256, 256, 0, stream>>>(y, scsh, out);
}